// Round 6
// baseline (150.540 us; speedup 1.0000x reference)
//
#include <hip/hip_runtime.h>
#include <hip/hip_bf16.h>

#define B_ 4
#define T_ 1024
#define C_ 512
#define H_ 8

typedef __attribute__((ext_vector_type(8))) short short8;
typedef __attribute__((ext_vector_type(4))) float floatx4;

__device__ __forceinline__ unsigned short f2bs(float f) {
    __hip_bfloat16 h = __float2bfloat16(f);
    return *(unsigned short*)&h;
}
__device__ __forceinline__ float bs2f(unsigned short u) {
    __hip_bfloat16 h;
    *(unsigned short*)&h = u;
    return __bfloat162float(h);
}

__device__ __forceinline__ void gload_lds16(const void* g, void* l) {
    __builtin_amdgcn_global_load_lds(
        (const __attribute__((address_space(1))) unsigned int*)g,
        (__attribute__((address_space(3))) unsigned int*)l, 16, 0, 0);
}

// ---------------------------------------------------------------------------
// prep:
//   blocks 0..1023   : Wq/Wk/Wv/Wo fp32 [k][n] -> bf16 transposed WT [n][k]
//   blocks 1024..3071: x, c fp32 -> bf16 row-major (Xb, Cb) for DMA staging
// ---------------------------------------------------------------------------
__global__ __launch_bounds__(256) void prep(
    const float* __restrict__ Wq, const float* __restrict__ Wk,
    const float* __restrict__ Wv, const float* __restrict__ Wo,
    const float* __restrict__ x, const float* __restrict__ cc,
    unsigned short* __restrict__ WT,
    unsigned short* __restrict__ Xb, unsigned short* __restrict__ Cb)
{
    __shared__ unsigned short tileT[32][33];
    const int r = blockIdx.x, tid = threadIdx.x;
    if (r < 1024) {
        const int w = r >> 8, tile = r & 255;
        const int k0 = (tile >> 4) * 32, n0 = (tile & 15) * 32;
        const float* W = (w == 0) ? Wq : (w == 1) ? Wk : (w == 2) ? Wv : Wo;
        unsigned short* out = WT + (size_t)w * 512 * 512;
        const int kk = tid >> 3, ns = (tid & 7) * 4;
        const float4 v = *(const float4*)&W[(size_t)(k0 + kk) * 512 + n0 + ns];
        tileT[ns + 0][kk] = f2bs(v.x);
        tileT[ns + 1][kk] = f2bs(v.y);
        tileT[ns + 2][kk] = f2bs(v.z);
        tileT[ns + 3][kk] = f2bs(v.w);
        __syncthreads();
        const int nn = tid >> 3, ks = (tid & 7) * 4;
        ushort4 o;
        o.x = tileT[nn][ks + 0]; o.y = tileT[nn][ks + 1];
        o.z = tileT[nn][ks + 2]; o.w = tileT[nn][ks + 3];
        *(ushort4*)&out[(size_t)(n0 + nn) * 512 + k0 + ks] = o;
    } else {
        const int bi = r - 1024;                 // 0..2047
        const bool isx = bi < 1024;
        const float* src = isx ? x : cc;
        unsigned short* dst = isx ? Xb : Cb;
        const int gid = ((bi & 1023) * 256 + tid) * 8;   // 8 floats/thread
        const float4 v0 = *(const float4*)&src[gid];
        const float4 v1 = *(const float4*)&src[gid + 4];
        ushort4 a, b;
        a.x = f2bs(v0.x); a.y = f2bs(v0.y); a.z = f2bs(v0.z); a.w = f2bs(v0.w);
        b.x = f2bs(v1.x); b.y = f2bs(v1.y); b.z = f2bs(v1.z); b.w = f2bs(v1.w);
        *(ushort4*)&dst[gid] = a;
        *(ushort4*)&dst[gid + 4] = b;
    }
}

// ---------------------------------------------------------------------------
// QKV projection GEMM, 128x128 tiles.  A (bf16 precvt) AND B via DMA.
// 3-buffer depth-2 pipeline: counted vmcnt + raw s_barrier.
// XCD-locality: grid (m=32, n=4, z=3) so bid%8 == m%8.
// Q,K -> [bh][t][64]; V -> [bh][d][t].  Q carries 1/sqrt(d)*log2(e).
// ---------------------------------------------------------------------------
__global__ __launch_bounds__(256) void qkv_mfma(
    const unsigned short* __restrict__ Xb, const unsigned short* __restrict__ Cb,
    const unsigned short* __restrict__ WT,
    const float* __restrict__ bq, const float* __restrict__ bk,
    const float* __restrict__ bv,
    unsigned short* __restrict__ Qc, unsigned short* __restrict__ Kc,
    unsigned short* __restrict__ Vtg)
{
    const int z = blockIdx.z;
    const unsigned short* Ab = (z == 0) ? Xb : Cb;
    const unsigned short* Bt = WT + (size_t)z * 262144;
    const float* bias = (z == 0) ? bq : (z == 1) ? bk : bv;
    const float scale = (z == 0) ? 0.18033688011112042f /* 0.125*log2(e) */ : 1.0f;

    __shared__ __align__(16) unsigned short sA[3 * 128 * 32];
    __shared__ __align__(16) unsigned short sB[3 * 128 * 32];

    const int tid = threadIdx.x;
    const int wave = tid >> 6, lane = tid & 63;
    const int m0 = blockIdx.x * 128, n0 = blockIdx.y * 128;   // XCD swizzle: m fast
    const int mrow = lane & 15, quad = lane >> 4, kgrp = quad * 8;
    const int mhalf = (wave & 1) * 64, noff = (wave >> 1) * 64;
    const int lrow = lane >> 2, lseg = (lane & 3) * 16;

    floatx4 acc[4][4];
    #pragma unroll
    for (int i = 0; i < 4; i++)
        #pragma unroll
        for (int j = 0; j < 4; j++)
            acc[i][j] = (floatx4){0.f, 0.f, 0.f, 0.f};

    auto stage = [&](int k0, int bufi) {
        #pragma unroll
        for (int j = 0; j < 2; j++) {
            const int rr = wave * 32 + j * 16 + lrow;
            gload_lds16((const char*)Ab + ((size_t)(m0 + rr) * 512 + k0) * 2 + lseg,
                        &sA[(size_t)(bufi * 128 + wave * 32 + j * 16) * 32]);
            gload_lds16((const char*)Bt + ((size_t)(n0 + rr) * 512 + k0) * 2 + lseg,
                        &sB[(size_t)(bufi * 128 + wave * 32 + j * 16) * 32]);
        }
    };

    stage(0, 0);
    stage(32, 1);
    for (int ck = 0; ck < 16; ck++) {
        const int buf = ck % 3;
        if (ck < 15) asm volatile("s_waitcnt vmcnt(4)" ::: "memory");
        else         asm volatile("s_waitcnt vmcnt(0)" ::: "memory");
        __builtin_amdgcn_s_barrier();
        __builtin_amdgcn_sched_barrier(0);
        if (ck < 14) stage((ck + 2) * 32, (ck + 2) % 3);
        const unsigned short* sAb = sA + (size_t)buf * 128 * 32;
        const unsigned short* sBb = sB + (size_t)buf * 128 * 32;
        short8 af[4], bfv[4];
        #pragma unroll
        for (int i = 0; i < 4; i++)
            af[i] = *(const short8*)&sAb[(size_t)(mhalf + i * 16 + mrow) * 32 + kgrp];
        #pragma unroll
        for (int i = 0; i < 4; i++)
            bfv[i] = *(const short8*)&sBb[(size_t)(noff + i * 16 + mrow) * 32 + kgrp];
        #pragma unroll
        for (int mt = 0; mt < 4; mt++)
            #pragma unroll
            for (int nt = 0; nt < 4; nt++)
                acc[mt][nt] = __builtin_amdgcn_mfma_f32_16x16x32_bf16(
                    af[mt], bfv[nt], acc[mt][nt], 0, 0, 0);
    }

    const int rowq = quad * 4;
    if (z < 2) {
        unsigned short* Y = (z == 0) ? Qc : Kc;
        #pragma unroll
        for (int nt = 0; nt < 4; nt++) {
            const int n = n0 + noff + nt * 16 + mrow;
            const float bv_ = bias[n];
            const int h = n >> 6, d = n & 63;
            #pragma unroll
            for (int mt = 0; mt < 4; mt++)
                #pragma unroll
                for (int r = 0; r < 4; r++) {
                    const int m = m0 + mhalf + mt * 16 + rowq + r;
                    const int bb = m >> 10, t = m & 1023;
                    Y[(((size_t)bb * H_ + h) * 1024 + t) * 64 + d] =
                        f2bs((acc[mt][nt][r] + bv_) * scale);
                }
        }
    } else {
        #pragma unroll
        for (int nt = 0; nt < 4; nt++) {
            const int n = n0 + noff + nt * 16 + mrow;
            const float bv_ = bias[n];
            const int h = n >> 6, d = n & 63;
            #pragma unroll
            for (int mt = 0; mt < 4; mt++) {
                const int m = m0 + mhalf + mt * 16 + rowq;
                const int bb = m >> 10, t = m & 1023;
                ushort4 o4;
                o4.x = f2bs(acc[mt][nt][0] + bv_);
                o4.y = f2bs(acc[mt][nt][1] + bv_);
                o4.z = f2bs(acc[mt][nt][2] + bv_);
                o4.w = f2bs(acc[mt][nt][3] + bv_);
                *(ushort4*)&Vtg[(((size_t)bb * H_ + h) * 64 + d) * 1024 + t] = o4;
            }
        }
    }
}

// ---------------------------------------------------------------------------
// Output projection GEMM, 128x64 tiles, bf16 A via DMA, 3-buffer depth-2
// pipeline (counted vmcnt + raw barrier).  XCD-locality: grid (m=32, n=8).
// ---------------------------------------------------------------------------
__global__ __launch_bounds__(256) void out_mfma(
    const unsigned short* __restrict__ AOb, const unsigned short* __restrict__ WoT,
    const float* __restrict__ bias, float* __restrict__ out)
{
    __shared__ __align__(16) unsigned short sA[3 * 128 * 32];
    __shared__ __align__(16) unsigned short sB[3 * 64 * 32];

    const int tid = threadIdx.x;
    const int wave = tid >> 6, lane = tid & 63;
    const int m0 = blockIdx.x * 128, n0 = blockIdx.y * 64;    // XCD swizzle: m fast
    const int mrow = lane & 15, quad = lane >> 4, kgrp = quad * 8;
    const int mhalf = (wave & 1) * 64, noff = (wave >> 1) * 32;
    const int lrow = lane >> 2, lseg = (lane & 3) * 16;

    floatx4 acc[4][2];
    #pragma unroll
    for (int i = 0; i < 4; i++)
        #pragma unroll
        for (int j = 0; j < 2; j++)
            acc[i][j] = (floatx4){0.f, 0.f, 0.f, 0.f};

    auto stage = [&](int k0, int bufi) {
        #pragma unroll
        for (int j = 0; j < 2; j++) {
            const int rA = wave * 32 + j * 16 + lrow;
            gload_lds16((const char*)AOb + ((size_t)(m0 + rA) * 512 + k0) * 2 + lseg,
                        &sA[(size_t)(bufi * 128 + wave * 32 + j * 16) * 32]);
        }
        const int rB = wave * 16 + lrow;
        gload_lds16((const char*)WoT + ((size_t)(n0 + rB) * 512 + k0) * 2 + lseg,
                    &sB[(size_t)(bufi * 64 + wave * 16) * 32]);
    };

    stage(0, 0);
    stage(32, 1);
    for (int ck = 0; ck < 16; ck++) {
        const int buf = ck % 3;
        if (ck < 15) asm volatile("s_waitcnt vmcnt(3)" ::: "memory");
        else         asm volatile("s_waitcnt vmcnt(0)" ::: "memory");
        __builtin_amdgcn_s_barrier();
        __builtin_amdgcn_sched_barrier(0);
        if (ck < 14) stage((ck + 2) * 32, (ck + 2) % 3);
        const unsigned short* sAb = sA + (size_t)buf * 128 * 32;
        const unsigned short* sBb = sB + (size_t)buf * 64 * 32;
        short8 af[4], bfv[2];
        #pragma unroll
        for (int i = 0; i < 4; i++)
            af[i] = *(const short8*)&sAb[(size_t)(mhalf + i * 16 + mrow) * 32 + kgrp];
        #pragma unroll
        for (int i = 0; i < 2; i++)
            bfv[i] = *(const short8*)&sBb[(size_t)(noff + i * 16 + mrow) * 32 + kgrp];
        #pragma unroll
        for (int mt = 0; mt < 4; mt++)
            #pragma unroll
            for (int nt = 0; nt < 2; nt++)
                acc[mt][nt] = __builtin_amdgcn_mfma_f32_16x16x32_bf16(
                    af[mt], bfv[nt], acc[mt][nt], 0, 0, 0);
    }

    const int rowq = quad * 4;
    #pragma unroll
    for (int nt = 0; nt < 2; nt++) {
        const int n = n0 + noff + nt * 16 + mrow;
        const float bv_ = bias[n];
        #pragma unroll
        for (int mt = 0; mt < 4; mt++)
            #pragma unroll
            for (int r = 0; r < 4; r++) {
                const int m = m0 + mhalf + mt * 16 + rowq + r;
                out[(size_t)m * 512 + n] = acc[mt][nt][r] + bv_;
            }
    }
}

// ---------------------------------------------------------------------------
// Attention: 128-row Q-tiles, 8 waves (512 thr), 256 blocks.  S^T trick
// (S^T = K Q^T), 3-buffer depth-2 DMA pipeline for K/V (counted vmcnt + raw
// barrier; 2 loads/thread/chunk -> vmcnt(2)), P bf16 in per-wave LDS, l
// complete in-block, band rel-v in epilogue.  Halved K/V staging vs 64-row
// tiles.  XCD-locality: grid (bh=32, tb=8) so bid%8 == bh%8.
// Scores are in log2 units (log2(e) folded into Qc) -> raw v_exp_f32.
// ---------------------------------------------------------------------------
__device__ __forceinline__ void attn_stage(
    const unsigned short* __restrict__ Kc, const unsigned short* __restrict__ Vtg,
    size_t qkbase, size_t vtbase, int s0, int wave, int ldrow, int gseg,
    unsigned short* KLb, unsigned short* VtLb)
{
    const int br = wave * 8;   // 8 waves x 8 rows = 64 rows per chunk
    gload_lds16((const char*)Kc + (qkbase + (size_t)(s0 + br + ldrow) * 64) * 2 + gseg * 16,
                &KLb[br * 64]);
    gload_lds16((const char*)Vtg + (vtbase + (size_t)(br + ldrow) * 1024 + s0) * 2 + gseg * 16,
                &VtLb[br * 64]);
}

__global__ __launch_bounds__(512) void attn_mfma(
    const unsigned short* __restrict__ Qc, const unsigned short* __restrict__ Kc,
    const unsigned short* __restrict__ Vtg,
    const float* __restrict__ rk, const float* __restrict__ rv,
    unsigned short* __restrict__ AOb)
{
    __shared__ __align__(16) unsigned short KL[3][64 * 64];
    __shared__ __align__(16) unsigned short VtL[3][64 * 64];
    __shared__ __align__(16) unsigned short PL[8][16 * 72];
    __shared__ float qbL[128 * 9];
    __shared__ float bandL[128 * 9];
    __shared__ float rvL[9 * 64];
    __shared__ float lL[128];

    const int bh = blockIdx.x, tb = blockIdx.y;   // XCD swizzle: bh fast
    const int b = bh >> 3, h = bh & 7;
    const int tid = threadIdx.x;
    const int wave = tid >> 6, lane = tid & 63;
    const int t0 = tb * 128;
    const int t0w = t0 + wave * 16;
    const size_t qkbase = (size_t)bh * T_ * 64;
    const size_t vtbase = (size_t)bh * 64 * T_;

    const int mrow = lane & 15;
    const int quad = lane >> 4;
    const int kgrp = quad * 8;
    const int x7 = mrow & 7;
    const int ldrow = lane >> 3;
    const int gseg = (lane & 7) ^ ldrow;

    attn_stage(Kc, Vtg, qkbase, vtbase, 0, wave, ldrow, gseg, &KL[0][0], &VtL[0][0]);
    attn_stage(Kc, Vtg, qkbase, vtbase, 64, wave, ldrow, gseg, &KL[1][0], &VtL[1][0]);

    for (int idx = tid; idx < 1152; idx += 512) {
        bandL[idx] = 0.f;
        const int row = idx / 9, w = idx - row * 9;
        const unsigned short* qp = &Qc[qkbase + (size_t)(t0 + row) * 64];
        float s0a = 0.f, s1a = 0.f, s2a = 0.f, s3a = 0.f;
        #pragma unroll
        for (int d8 = 0; d8 < 8; d8 += 4) {
            const short8 q0 = *(const short8*)&qp[d8 * 8];
            const short8 q1 = *(const short8*)&qp[(d8 + 1) * 8];
            const short8 q2 = *(const short8*)&qp[(d8 + 2) * 8];
            const short8 q3 = *(const short8*)&qp[(d8 + 3) * 8];
            #pragma unroll
            for (int i = 0; i < 8; i++) {
                s0a = fmaf(bs2f((unsigned short)q0[i]), rk[w * 64 + d8 * 8 + i], s0a);
                s1a = fmaf(bs2f((unsigned short)q1[i]), rk[w * 64 + (d8 + 1) * 8 + i], s1a);
                s2a = fmaf(bs2f((unsigned short)q2[i]), rk[w * 64 + (d8 + 2) * 8 + i], s2a);
                s3a = fmaf(bs2f((unsigned short)q3[i]), rk[w * 64 + (d8 + 3) * 8 + i], s3a);
            }
        }
        qbL[idx] = (s0a + s1a) + (s2a + s3a);
    }
    if (tid < 512) {
        for (int idx = tid; idx < 576; idx += 512) rvL[idx] = rv[idx];
    }

    const short8 aQ0 = *(const short8*)&Qc[qkbase + (size_t)(t0w + mrow) * 64 + kgrp];
    const short8 aQ1 = *(const short8*)&Qc[qkbase + (size_t)(t0w + mrow) * 64 + 32 + kgrp];

    floatx4 Oc[4];
    float lsA[4] = {0.f, 0.f, 0.f, 0.f};
    #pragma unroll
    for (int dt = 0; dt < 4; dt++) Oc[dt] = (floatx4){0.f, 0.f, 0.f, 0.f};

    unsigned short* Pw = &PL[wave][0];
    float* qbw = &qbL[wave * 16 * 9];
    float* bandw = &bandL[wave * 16 * 9];

    __syncthreads();   // qbL/rvL visibility

    for (int ck = 0; ck < 16; ck++) {
        const int s0 = ck * 64;
        const int buf = ck % 3;
        if (ck < 15) asm volatile("s_waitcnt vmcnt(2)" ::: "memory");
        else         asm volatile("s_waitcnt vmcnt(0)" ::: "memory");
        __builtin_amdgcn_s_barrier();
        __builtin_amdgcn_sched_barrier(0);
        if (ck < 14)
            attn_stage(Kc, Vtg, qkbase, vtbase, s0 + 128, wave, ldrow, gseg,
                       &KL[(ck + 2) % 3][0], &VtL[(ck + 2) % 3][0]);

        floatx4 Sc[4];
        #pragma unroll
        for (int st = 0; st < 4; st++) {
            const int row = st * 16 + mrow;
            const short8 aK0 = *(const short8*)&KL[buf][row * 64 + (quad ^ x7) * 8];
            const short8 aK1 = *(const short8*)&KL[buf][row * 64 + ((4 + quad) ^ x7) * 8];
            floatx4 s4 = {0.f, 0.f, 0.f, 0.f};
            s4 = __builtin_amdgcn_mfma_f32_16x16x32_bf16(aK0, aQ0, s4, 0, 0, 0);
            s4 = __builtin_amdgcn_mfma_f32_16x16x32_bf16(aK1, aQ1, s4, 0, 0, 0);
            Sc[st] = s4;
        }

        #pragma unroll
        for (int st = 0; st < 4; st++) {
            const int diff = s0 + st * 16 - t0w;
            float p0, p1, p2, p3;
            if (diff >= -19 && diff <= 19) {
                #pragma unroll
                for (int r = 0; r < 4; r++) {
                    const int rel = diff + quad * 4 + r - mrow;
                    float sc = Sc[st][r];
                    const bool inband = (rel >= -4) && (rel <= 4);
                    if (inband) sc += qbw[mrow * 9 + rel + 4];
                    const float p = __builtin_amdgcn_exp2f(sc);
                    if (inband) bandw[mrow * 9 + rel + 4] = p;
                    Sc[st][r] = p;
                }
            } else {
                #pragma unroll
                for (int r = 0; r < 4; r++)
                    Sc[st][r] = __builtin_amdgcn_exp2f(Sc[st][r]);
            }
            p0 = Sc[st][0]; p1 = Sc[st][1]; p2 = Sc[st][2]; p3 = Sc[st][3];
            lsA[st] += (p0 + p1) + (p2 + p3);
            ushort4 o4;
            o4.x = f2bs(p0); o4.y = f2bs(p1); o4.z = f2bs(p2); o4.w = f2bs(p3);
            *(ushort4*)&Pw[mrow * 72 + st * 16 + quad * 4] = o4;
        }

        #pragma unroll
        for (int c = 0; c < 2; c++) {
            const short8 aP = *(const short8*)&Pw[mrow * 72 + c * 32 + kgrp];
            #pragma unroll
            for (int dt = 0; dt < 4; dt++) {
                const int segl = (c * 4 + quad) ^ x7;
                const short8 bV = *(const short8*)&VtL[buf][(dt * 16 + mrow) * 64 + segl * 8];
                Oc[dt] = __builtin_amdgcn_mfma_f32_16x16x32_bf16(aP, bV, Oc[dt], 0, 0, 0);
            }
        }
    }

    float lv = (lsA[0] + lsA[1]) + (lsA[2] + lsA[3]);
    lv += __shfl_xor(lv, 16);
    lv += __shfl_xor(lv, 32);
    if (quad == 0) lL[wave * 16 + mrow] = lv;

    #pragma unroll
    for (int r = 0; r < 4; r++) {
        const int tl = quad * 4 + r;
        const float inv = 1.f / lL[wave * 16 + tl];
        #pragma unroll
        for (int w = 0; w < 9; w++) {
            const float p = bandw[tl * 9 + w];
            #pragma unroll
            for (int dt = 0; dt < 4; dt++)
                Oc[dt][r] = fmaf(p, rvL[w * 64 + dt * 16 + mrow], Oc[dt][r]);
        }
        const int t = t0w + tl;
        #pragma unroll
        for (int dt = 0; dt < 4; dt++)
            AOb[((size_t)b * 1024 + t) * 512 + h * 64 + dt * 16 + mrow] =
                f2bs(Oc[dt][r] * inv);
    }
}

// ---------------------------------------------------------------------------
extern "C" void kernel_launch(void* const* d_in, const int* in_sizes, int n_in,
                              void* d_out, int out_size, void* d_ws, size_t ws_size,
                              hipStream_t stream)
{
    const float* x  = (const float*)d_in[0];
    const float* c  = (const float*)d_in[1];
    const float* Wq = (const float*)d_in[2];
    const float* bq = (const float*)d_in[3];
    const float* Wk = (const float*)d_in[4];
    const float* bk = (const float*)d_in[5];
    const float* Wv = (const float*)d_in[6];
    const float* bv = (const float*)d_in[7];
    const float* Wo = (const float*)d_in[8];
    const float* bo = (const float*)d_in[9];
    const float* rk = (const float*)d_in[10];
    const float* rv = (const float*)d_in[11];

    unsigned short* WT  = (unsigned short*)d_ws;           // 4x [512n][512k] bf16
    unsigned short* Qc  = WT + (size_t)4 * 512 * 512;      // [32][1024][64] bf16
    unsigned short* Kc  = Qc + (size_t)32 * 1024 * 64;
    unsigned short* Vtg = Kc + (size_t)32 * 1024 * 64;     // [32][64][1024] bf16
    unsigned short* AOb = Vtg + (size_t)32 * 1024 * 64;    // [4096][512] bf16
    unsigned short* Xb  = AOb + (size_t)4096 * 512;        // [4096][512] bf16
    unsigned short* Cb  = Xb + (size_t)4096 * 512;         // [4096][512] bf16

    prep<<<3072, 256, 0, stream>>>(Wq, Wk, Wv, Wo, x, c, WT, Xb, Cb);
    qkv_mfma<<<dim3(32, 4, 3), 256, 0, stream>>>(Xb, Cb, WT, bq, bk, bv, Qc, Kc, Vtg);
    attn_mfma<<<dim3(32, 8), 512, 0, stream>>>(Qc, Kc, Vtg, rk, rv, AOb);
    out_mfma<<<dim3(32, 8), 256, 0, stream>>>(AOb, WT + (size_t)3 * 262144, bo, (float*)d_out);
}

// Round 7
// 147.715 us; speedup vs baseline: 1.0191x; 1.0191x over previous
//
#include <hip/hip_runtime.h>
#include <hip/hip_bf16.h>

#define B_ 4
#define T_ 1024
#define C_ 512
#define H_ 8

typedef __attribute__((ext_vector_type(8))) short short8;
typedef __attribute__((ext_vector_type(4))) float floatx4;

__device__ __forceinline__ unsigned short f2bs(float f) {
    __hip_bfloat16 h = __float2bfloat16(f);
    return *(unsigned short*)&h;
}
__device__ __forceinline__ float bs2f(unsigned short u) {
    __hip_bfloat16 h;
    *(unsigned short*)&h = u;
    return __bfloat162float(h);
}

__device__ __forceinline__ void gload_lds16(const void* g, void* l) {
    __builtin_amdgcn_global_load_lds(
        (const __attribute__((address_space(1))) unsigned int*)g,
        (__attribute__((address_space(3))) unsigned int*)l, 16, 0, 0);
}

// ---------------------------------------------------------------------------
// prep:
//   blocks 0..1023   : Wq/Wk/Wv/Wo fp32 [k][n] -> bf16 transposed WT [n][k]
//   blocks 1024..3071: x, c fp32 -> bf16 row-major (Xb, Cb) for DMA staging
// ---------------------------------------------------------------------------
__global__ __launch_bounds__(256) void prep(
    const float* __restrict__ Wq, const float* __restrict__ Wk,
    const float* __restrict__ Wv, const float* __restrict__ Wo,
    const float* __restrict__ x, const float* __restrict__ cc,
    unsigned short* __restrict__ WT,
    unsigned short* __restrict__ Xb, unsigned short* __restrict__ Cb)
{
    __shared__ unsigned short tileT[32][33];
    const int r = blockIdx.x, tid = threadIdx.x;
    if (r < 1024) {
        const int w = r >> 8, tile = r & 255;
        const int k0 = (tile >> 4) * 32, n0 = (tile & 15) * 32;
        const float* W = (w == 0) ? Wq : (w == 1) ? Wk : (w == 2) ? Wv : Wo;
        unsigned short* out = WT + (size_t)w * 512 * 512;
        const int kk = tid >> 3, ns = (tid & 7) * 4;
        const float4 v = *(const float4*)&W[(size_t)(k0 + kk) * 512 + n0 + ns];
        tileT[ns + 0][kk] = f2bs(v.x);
        tileT[ns + 1][kk] = f2bs(v.y);
        tileT[ns + 2][kk] = f2bs(v.z);
        tileT[ns + 3][kk] = f2bs(v.w);
        __syncthreads();
        const int nn = tid >> 3, ks = (tid & 7) * 4;
        ushort4 o;
        o.x = tileT[nn][ks + 0]; o.y = tileT[nn][ks + 1];
        o.z = tileT[nn][ks + 2]; o.w = tileT[nn][ks + 3];
        *(ushort4*)&out[(size_t)(n0 + nn) * 512 + k0 + ks] = o;
    } else {
        const int bi = r - 1024;                 // 0..2047
        const bool isx = bi < 1024;
        const float* src = isx ? x : cc;
        unsigned short* dst = isx ? Xb : Cb;
        const int gid = ((bi & 1023) * 256 + tid) * 8;   // 8 floats/thread
        const float4 v0 = *(const float4*)&src[gid];
        const float4 v1 = *(const float4*)&src[gid + 4];
        ushort4 a, b;
        a.x = f2bs(v0.x); a.y = f2bs(v0.y); a.z = f2bs(v0.z); a.w = f2bs(v0.w);
        b.x = f2bs(v1.x); b.y = f2bs(v1.y); b.z = f2bs(v1.z); b.w = f2bs(v1.w);
        *(ushort4*)&dst[gid] = a;
        *(ushort4*)&dst[gid + 4] = b;
    }
}

// ---------------------------------------------------------------------------
// QKV projection GEMM, 128x128 tiles.  A (bf16 precvt) AND B via DMA.
// 3-buffer depth-2 pipeline: counted vmcnt + raw s_barrier.
// XCD-locality: grid (m=32, n=4, z=3) so bid%8 == m%8.
// Q,K -> [bh][t][64]; V -> [bh][d][t].  Q carries 1/sqrt(d)*log2(e).
// ---------------------------------------------------------------------------
__global__ __launch_bounds__(256) void qkv_mfma(
    const unsigned short* __restrict__ Xb, const unsigned short* __restrict__ Cb,
    const unsigned short* __restrict__ WT,
    const float* __restrict__ bq, const float* __restrict__ bk,
    const float* __restrict__ bv,
    unsigned short* __restrict__ Qc, unsigned short* __restrict__ Kc,
    unsigned short* __restrict__ Vtg)
{
    const int z = blockIdx.z;
    const unsigned short* Ab = (z == 0) ? Xb : Cb;
    const unsigned short* Bt = WT + (size_t)z * 262144;
    const float* bias = (z == 0) ? bq : (z == 1) ? bk : bv;
    const float scale = (z == 0) ? 0.18033688011112042f /* 0.125*log2(e) */ : 1.0f;

    __shared__ __align__(16) unsigned short sA[3 * 128 * 32];
    __shared__ __align__(16) unsigned short sB[3 * 128 * 32];

    const int tid = threadIdx.x;
    const int wave = tid >> 6, lane = tid & 63;
    const int m0 = blockIdx.x * 128, n0 = blockIdx.y * 128;   // XCD swizzle: m fast
    const int mrow = lane & 15, quad = lane >> 4, kgrp = quad * 8;
    const int mhalf = (wave & 1) * 64, noff = (wave >> 1) * 64;
    const int lrow = lane >> 2, lseg = (lane & 3) * 16;

    floatx4 acc[4][4];
    #pragma unroll
    for (int i = 0; i < 4; i++)
        #pragma unroll
        for (int j = 0; j < 4; j++)
            acc[i][j] = (floatx4){0.f, 0.f, 0.f, 0.f};

    auto stage = [&](int k0, int bufi) {
        #pragma unroll
        for (int j = 0; j < 2; j++) {
            const int rr = wave * 32 + j * 16 + lrow;
            gload_lds16((const char*)Ab + ((size_t)(m0 + rr) * 512 + k0) * 2 + lseg,
                        &sA[(size_t)(bufi * 128 + wave * 32 + j * 16) * 32]);
            gload_lds16((const char*)Bt + ((size_t)(n0 + rr) * 512 + k0) * 2 + lseg,
                        &sB[(size_t)(bufi * 128 + wave * 32 + j * 16) * 32]);
        }
    };

    stage(0, 0);
    stage(32, 1);
    for (int ck = 0; ck < 16; ck++) {
        const int buf = ck % 3;
        if (ck < 15) asm volatile("s_waitcnt vmcnt(4)" ::: "memory");
        else         asm volatile("s_waitcnt vmcnt(0)" ::: "memory");
        __builtin_amdgcn_s_barrier();
        __builtin_amdgcn_sched_barrier(0);
        if (ck < 14) stage((ck + 2) * 32, (ck + 2) % 3);
        const unsigned short* sAb = sA + (size_t)buf * 128 * 32;
        const unsigned short* sBb = sB + (size_t)buf * 128 * 32;
        short8 af[4], bfv[4];
        #pragma unroll
        for (int i = 0; i < 4; i++)
            af[i] = *(const short8*)&sAb[(size_t)(mhalf + i * 16 + mrow) * 32 + kgrp];
        #pragma unroll
        for (int i = 0; i < 4; i++)
            bfv[i] = *(const short8*)&sBb[(size_t)(noff + i * 16 + mrow) * 32 + kgrp];
        #pragma unroll
        for (int mt = 0; mt < 4; mt++)
            #pragma unroll
            for (int nt = 0; nt < 4; nt++)
                acc[mt][nt] = __builtin_amdgcn_mfma_f32_16x16x32_bf16(
                    af[mt], bfv[nt], acc[mt][nt], 0, 0, 0);
    }

    const int rowq = quad * 4;
    if (z < 2) {
        unsigned short* Y = (z == 0) ? Qc : Kc;
        #pragma unroll
        for (int nt = 0; nt < 4; nt++) {
            const int n = n0 + noff + nt * 16 + mrow;
            const float bv_ = bias[n];
            const int h = n >> 6, d = n & 63;
            #pragma unroll
            for (int mt = 0; mt < 4; mt++)
                #pragma unroll
                for (int r = 0; r < 4; r++) {
                    const int m = m0 + mhalf + mt * 16 + rowq + r;
                    const int bb = m >> 10, t = m & 1023;
                    Y[(((size_t)bb * H_ + h) * 1024 + t) * 64 + d] =
                        f2bs((acc[mt][nt][r] + bv_) * scale);
                }
        }
    } else {
        #pragma unroll
        for (int nt = 0; nt < 4; nt++) {
            const int n = n0 + noff + nt * 16 + mrow;
            const float bv_ = bias[n];
            const int h = n >> 6, d = n & 63;
            #pragma unroll
            for (int mt = 0; mt < 4; mt++) {
                const int m = m0 + mhalf + mt * 16 + rowq;
                const int bb = m >> 10, t = m & 1023;
                ushort4 o4;
                o4.x = f2bs(acc[mt][nt][0] + bv_);
                o4.y = f2bs(acc[mt][nt][1] + bv_);
                o4.z = f2bs(acc[mt][nt][2] + bv_);
                o4.w = f2bs(acc[mt][nt][3] + bv_);
                *(ushort4*)&Vtg[(((size_t)bb * H_ + h) * 64 + d) * 1024 + t] = o4;
            }
        }
    }
}

// ---------------------------------------------------------------------------
// Output projection GEMM, 128x64 tiles, bf16 A via DMA, 3-buffer depth-2
// pipeline (counted vmcnt + raw barrier).  XCD-locality: grid (m=32, n=8).
// ---------------------------------------------------------------------------
__global__ __launch_bounds__(256) void out_mfma(
    const unsigned short* __restrict__ AOb, const unsigned short* __restrict__ WoT,
    const float* __restrict__ bias, float* __restrict__ out)
{
    __shared__ __align__(16) unsigned short sA[3 * 128 * 32];
    __shared__ __align__(16) unsigned short sB[3 * 64 * 32];

    const int tid = threadIdx.x;
    const int wave = tid >> 6, lane = tid & 63;
    const int m0 = blockIdx.x * 128, n0 = blockIdx.y * 64;    // XCD swizzle: m fast
    const int mrow = lane & 15, quad = lane >> 4, kgrp = quad * 8;
    const int mhalf = (wave & 1) * 64, noff = (wave >> 1) * 32;
    const int lrow = lane >> 2, lseg = (lane & 3) * 16;

    floatx4 acc[4][2];
    #pragma unroll
    for (int i = 0; i < 4; i++)
        #pragma unroll
        for (int j = 0; j < 2; j++)
            acc[i][j] = (floatx4){0.f, 0.f, 0.f, 0.f};

    auto stage = [&](int k0, int bufi) {
        #pragma unroll
        for (int j = 0; j < 2; j++) {
            const int rA = wave * 32 + j * 16 + lrow;
            gload_lds16((const char*)AOb + ((size_t)(m0 + rA) * 512 + k0) * 2 + lseg,
                        &sA[(size_t)(bufi * 128 + wave * 32 + j * 16) * 32]);
        }
        const int rB = wave * 16 + lrow;
        gload_lds16((const char*)WoT + ((size_t)(n0 + rB) * 512 + k0) * 2 + lseg,
                    &sB[(size_t)(bufi * 64 + wave * 16) * 32]);
    };

    stage(0, 0);
    stage(32, 1);
    for (int ck = 0; ck < 16; ck++) {
        const int buf = ck % 3;
        if (ck < 15) asm volatile("s_waitcnt vmcnt(3)" ::: "memory");
        else         asm volatile("s_waitcnt vmcnt(0)" ::: "memory");
        __builtin_amdgcn_s_barrier();
        __builtin_amdgcn_sched_barrier(0);
        if (ck < 14) stage((ck + 2) * 32, (ck + 2) % 3);
        const unsigned short* sAb = sA + (size_t)buf * 128 * 32;
        const unsigned short* sBb = sB + (size_t)buf * 64 * 32;
        short8 af[4], bfv[2];
        #pragma unroll
        for (int i = 0; i < 4; i++)
            af[i] = *(const short8*)&sAb[(size_t)(mhalf + i * 16 + mrow) * 32 + kgrp];
        #pragma unroll
        for (int i = 0; i < 2; i++)
            bfv[i] = *(const short8*)&sBb[(size_t)(noff + i * 16 + mrow) * 32 + kgrp];
        #pragma unroll
        for (int mt = 0; mt < 4; mt++)
            #pragma unroll
            for (int nt = 0; nt < 2; nt++)
                acc[mt][nt] = __builtin_amdgcn_mfma_f32_16x16x32_bf16(
                    af[mt], bfv[nt], acc[mt][nt], 0, 0, 0);
    }

    const int rowq = quad * 4;
    #pragma unroll
    for (int nt = 0; nt < 2; nt++) {
        const int n = n0 + noff + nt * 16 + mrow;
        const float bv_ = bias[n];
        #pragma unroll
        for (int mt = 0; mt < 4; mt++)
            #pragma unroll
            for (int r = 0; r < 4; r++) {
                const int m = m0 + mhalf + mt * 16 + rowq + r;
                out[(size_t)m * 512 + n] = acc[mt][nt][r] + bv_;
            }
    }
}

// ---------------------------------------------------------------------------
// Attention: full s-range per block, 512 blocks.  S^T trick (S^T = K Q^T),
// 3-buffer depth-2 DMA pipeline for K/V (counted vmcnt + raw barrier),
// P bf16 in per-wave LDS, l complete in-block, band rel-v in epilogue.
// XCD-locality: grid (bh=32, tb=16) so bid%8 == bh%8 -- all 16 Q-tile blocks
// sharing one head's 256 KB K/V land on the same XCD (4 heads per L2).
// Scores are in log2 units (log2(e) folded into Qc) -> raw v_exp_f32.
// ---------------------------------------------------------------------------
__device__ __forceinline__ void attn_stage(
    const unsigned short* __restrict__ Kc, const unsigned short* __restrict__ Vtg,
    size_t qkbase, size_t vtbase, int s0, int wave, int ldrow, int gseg,
    unsigned short* KLb, unsigned short* VtLb)
{
    #pragma unroll
    for (int j = 0; j < 2; j++) {
        const int br = wave * 16 + j * 8;
        gload_lds16((const char*)Kc + (qkbase + (size_t)(s0 + br + ldrow) * 64) * 2 + gseg * 16,
                    &KLb[br * 64]);
        gload_lds16((const char*)Vtg + (vtbase + (size_t)(br + ldrow) * 1024 + s0) * 2 + gseg * 16,
                    &VtLb[br * 64]);
    }
}

__global__ __launch_bounds__(256) void attn_mfma(
    const unsigned short* __restrict__ Qc, const unsigned short* __restrict__ Kc,
    const unsigned short* __restrict__ Vtg,
    const float* __restrict__ rk, const float* __restrict__ rv,
    unsigned short* __restrict__ AOb)
{
    __shared__ __align__(16) unsigned short KL[3][64 * 64];
    __shared__ __align__(16) unsigned short VtL[3][64 * 64];
    __shared__ __align__(16) unsigned short PL[4][16 * 72];
    __shared__ float qbL[64 * 9];
    __shared__ float bandL[64 * 9];
    __shared__ float rvL[9 * 64];
    __shared__ float lL[64];

    const int bh = blockIdx.x, tb = blockIdx.y;   // XCD swizzle: bh fast
    const int b = bh >> 3, h = bh & 7;
    const int tid = threadIdx.x;
    const int wave = tid >> 6, lane = tid & 63;
    const int t0 = tb * 64;
    const int t0w = t0 + wave * 16;
    const size_t qkbase = (size_t)bh * T_ * 64;
    const size_t vtbase = (size_t)bh * 64 * T_;

    const int mrow = lane & 15;
    const int quad = lane >> 4;
    const int kgrp = quad * 8;
    const int x7 = mrow & 7;
    const int ldrow = lane >> 3;
    const int gseg = (lane & 7) ^ ldrow;

    attn_stage(Kc, Vtg, qkbase, vtbase, 0, wave, ldrow, gseg, &KL[0][0], &VtL[0][0]);
    attn_stage(Kc, Vtg, qkbase, vtbase, 64, wave, ldrow, gseg, &KL[1][0], &VtL[1][0]);

    for (int idx = tid; idx < 576; idx += 256) {
        bandL[idx] = 0.f;
        rvL[idx] = rv[idx];
        const int row = idx / 9, w = idx - row * 9;
        const unsigned short* qp = &Qc[qkbase + (size_t)(t0 + row) * 64];
        float s0a = 0.f, s1a = 0.f, s2a = 0.f, s3a = 0.f;
        #pragma unroll
        for (int d8 = 0; d8 < 8; d8 += 4) {
            const short8 q0 = *(const short8*)&qp[d8 * 8];
            const short8 q1 = *(const short8*)&qp[(d8 + 1) * 8];
            const short8 q2 = *(const short8*)&qp[(d8 + 2) * 8];
            const short8 q3 = *(const short8*)&qp[(d8 + 3) * 8];
            #pragma unroll
            for (int i = 0; i < 8; i++) {
                s0a = fmaf(bs2f((unsigned short)q0[i]), rk[w * 64 + d8 * 8 + i], s0a);
                s1a = fmaf(bs2f((unsigned short)q1[i]), rk[w * 64 + (d8 + 1) * 8 + i], s1a);
                s2a = fmaf(bs2f((unsigned short)q2[i]), rk[w * 64 + (d8 + 2) * 8 + i], s2a);
                s3a = fmaf(bs2f((unsigned short)q3[i]), rk[w * 64 + (d8 + 3) * 8 + i], s3a);
            }
        }
        qbL[idx] = (s0a + s1a) + (s2a + s3a);
    }

    const short8 aQ0 = *(const short8*)&Qc[qkbase + (size_t)(t0w + mrow) * 64 + kgrp];
    const short8 aQ1 = *(const short8*)&Qc[qkbase + (size_t)(t0w + mrow) * 64 + 32 + kgrp];

    floatx4 Oc[4];
    float lsA[4] = {0.f, 0.f, 0.f, 0.f};
    #pragma unroll
    for (int dt = 0; dt < 4; dt++) Oc[dt] = (floatx4){0.f, 0.f, 0.f, 0.f};

    unsigned short* Pw = &PL[wave][0];
    float* qbw = &qbL[wave * 16 * 9];
    float* bandw = &bandL[wave * 16 * 9];

    __syncthreads();   // qbL/rvL visibility

    for (int ck = 0; ck < 16; ck++) {
        const int s0 = ck * 64;
        const int buf = ck % 3;
        if (ck < 15) asm volatile("s_waitcnt vmcnt(4)" ::: "memory");
        else         asm volatile("s_waitcnt vmcnt(0)" ::: "memory");
        __builtin_amdgcn_s_barrier();
        __builtin_amdgcn_sched_barrier(0);
        if (ck < 14)
            attn_stage(Kc, Vtg, qkbase, vtbase, s0 + 128, wave, ldrow, gseg,
                       &KL[(ck + 2) % 3][0], &VtL[(ck + 2) % 3][0]);

        floatx4 Sc[4];
        #pragma unroll
        for (int st = 0; st < 4; st++) {
            const int row = st * 16 + mrow;
            const short8 aK0 = *(const short8*)&KL[buf][row * 64 + (quad ^ x7) * 8];
            const short8 aK1 = *(const short8*)&KL[buf][row * 64 + ((4 + quad) ^ x7) * 8];
            floatx4 s4 = {0.f, 0.f, 0.f, 0.f};
            s4 = __builtin_amdgcn_mfma_f32_16x16x32_bf16(aK0, aQ0, s4, 0, 0, 0);
            s4 = __builtin_amdgcn_mfma_f32_16x16x32_bf16(aK1, aQ1, s4, 0, 0, 0);
            Sc[st] = s4;
        }

        #pragma unroll
        for (int st = 0; st < 4; st++) {
            const int diff = s0 + st * 16 - t0w;
            float p0, p1, p2, p3;
            if (diff >= -19 && diff <= 19) {
                #pragma unroll
                for (int r = 0; r < 4; r++) {
                    const int rel = diff + quad * 4 + r - mrow;
                    float sc = Sc[st][r];
                    const bool inband = (rel >= -4) && (rel <= 4);
                    if (inband) sc += qbw[mrow * 9 + rel + 4];
                    const float p = __builtin_amdgcn_exp2f(sc);
                    if (inband) bandw[mrow * 9 + rel + 4] = p;
                    Sc[st][r] = p;
                }
            } else {
                #pragma unroll
                for (int r = 0; r < 4; r++)
                    Sc[st][r] = __builtin_amdgcn_exp2f(Sc[st][r]);
            }
            p0 = Sc[st][0]; p1 = Sc[st][1]; p2 = Sc[st][2]; p3 = Sc[st][3];
            lsA[st] += (p0 + p1) + (p2 + p3);
            ushort4 o4;
            o4.x = f2bs(p0); o4.y = f2bs(p1); o4.z = f2bs(p2); o4.w = f2bs(p3);
            *(ushort4*)&Pw[mrow * 72 + st * 16 + quad * 4] = o4;
        }

        #pragma unroll
        for (int c = 0; c < 2; c++) {
            const short8 aP = *(const short8*)&Pw[mrow * 72 + c * 32 + kgrp];
            #pragma unroll
            for (int dt = 0; dt < 4; dt++) {
                const int segl = (c * 4 + quad) ^ x7;
                const short8 bV = *(const short8*)&VtL[buf][(dt * 16 + mrow) * 64 + segl * 8];
                Oc[dt] = __builtin_amdgcn_mfma_f32_16x16x32_bf16(aP, bV, Oc[dt], 0, 0, 0);
            }
        }
    }

    float lv = (lsA[0] + lsA[1]) + (lsA[2] + lsA[3]);
    lv += __shfl_xor(lv, 16);
    lv += __shfl_xor(lv, 32);
    if (quad == 0) lL[wave * 16 + mrow] = lv;

    #pragma unroll
    for (int r = 0; r < 4; r++) {
        const int tl = quad * 4 + r;
        const float inv = 1.f / lL[wave * 16 + tl];
        #pragma unroll
        for (int w = 0; w < 9; w++) {
            const float p = bandw[tl * 9 + w];
            #pragma unroll
            for (int dt = 0; dt < 4; dt++)
                Oc[dt][r] = fmaf(p, rvL[w * 64 + dt * 16 + mrow], Oc[dt][r]);
        }
        const int t = t0w + tl;
        #pragma unroll
        for (int dt = 0; dt < 4; dt++)
            AOb[((size_t)b * 1024 + t) * 512 + h * 64 + dt * 16 + mrow] =
                f2bs(Oc[dt][r] * inv);
    }
}

// ---------------------------------------------------------------------------
extern "C" void kernel_launch(void* const* d_in, const int* in_sizes, int n_in,
                              void* d_out, int out_size, void* d_ws, size_t ws_size,
                              hipStream_t stream)
{
    const float* x  = (const float*)d_in[0];
    const float* c  = (const float*)d_in[1];
    const float* Wq = (const float*)d_in[2];
    const float* bq = (const float*)d_in[3];
    const float* Wk = (const float*)d_in[4];
    const float* bk = (const float*)d_in[5];
    const float* Wv = (const float*)d_in[6];
    const float* bv = (const float*)d_in[7];
    const float* Wo = (const float*)d_in[8];
    const float* bo = (const float*)d_in[9];
    const float* rk = (const float*)d_in[10];
    const float* rv = (const float*)d_in[11];

    unsigned short* WT  = (unsigned short*)d_ws;           // 4x [512n][512k] bf16
    unsigned short* Qc  = WT + (size_t)4 * 512 * 512;      // [32][1024][64] bf16
    unsigned short* Kc  = Qc + (size_t)32 * 1024 * 64;
    unsigned short* Vtg = Kc + (size_t)32 * 1024 * 64;     // [32][64][1024] bf16
    unsigned short* AOb = Vtg + (size_t)32 * 1024 * 64;    // [4096][512] bf16
    unsigned short* Xb  = AOb + (size_t)4096 * 512;        // [4096][512] bf16
    unsigned short* Cb  = Xb + (size_t)4096 * 512;         // [4096][512] bf16

    prep<<<3072, 256, 0, stream>>>(Wq, Wk, Wv, Wo, x, c, WT, Xb, Cb);
    qkv_mfma<<<dim3(32, 4, 3), 256, 0, stream>>>(Xb, Cb, WT, bq, bk, bv, Qc, Kc, Vtg);
    attn_mfma<<<dim3(32, 16), 256, 0, stream>>>(Qc, Kc, Vtg, rk, rv, AOb);
    out_mfma<<<dim3(32, 8), 256, 0, stream>>>(AOb, WT + (size_t)3 * 262144, bo, (float*)d_out);
}